// Round 8
// baseline (111.316 us; speedup 1.0000x reference)
//
#include <hip/hip_runtime.h>

#define NUM_A    400000
#define NUM_G    64
#define TOPK     10
#define CHUNKS   64
#define CHUNK_SZ (NUM_A / CHUNKS)   // 6250
#define GGROUP   8                  // GTs per K1 block (= waves per block)
#define NGROUPS  (NUM_G / GGROUP)   // 8
#define BLK      512                // 8 waves
#define CAP      768                // per-GT candidate cap per chunk
                                    // (mean in-box <= 250, SD ~16 -> 32 SD margin)
#define SENT_I   0x7fffffff

// top_k ordering: larger value first; ties -> lower anchor index first.
// Sentinel (0.0f, SENT_I) sorts after every real candidate.
__device__ __forceinline__ bool better(float m1, int a1, float m2, int a2) {
    return (m1 > m2) || ((m1 == m2) && (a1 < a2));
}

// IoU-metric; arithmetic order identical to rounds 2-7 (absmax=0 vs numpy).
__device__ __forceinline__ float iou_metric(
    float px1, float py1, float px2, float py2, float parea, float score,
    float gx1, float gy1, float gx2, float gy2, float garea)
{
    float ltx = fmaxf(px1, gx1);
    float lty = fmaxf(py1, gy1);
    float rbx = fminf(px2, gx2);
    float rby = fminf(py2, gy2);
    float w = fmaxf(rbx - ltx, 0.0f);
    float h = fmaxf(rby - lty, 0.0f);
    float inter = w * h;
    float iou = inter / (parea + garea - inter);   // denom >= 64 always
    float iou2 = iou * iou;
    float iou6 = iou2 * iou2 * iou2;
    return score * iou6;
}

// Wave-wide (64-lane) butterfly max of (value, anchor) under better().
__device__ __forceinline__ void wave_max_pair(float& bv, int& bi) {
#pragma unroll
    for (int s = 1; s < 64; s <<= 1) {
        float ov = __shfl_xor(bv, s, 64);
        int   oi = __shfl_xor(bi, s, 64);
        if (better(ov, oi, bv, bi)) { bv = ov; bi = oi; }
    }
}

// Wave-aggregated LDS list append: one atomic per wave per ballot instead of
// per-lane divergent atomic branches (round-7's phase-A bottleneck).
__device__ __forceinline__ void ballot_append(
    bool in, int a, int* cnt, int* list, int lane)
{
    unsigned long long mask = __ballot(in);
    if (mask) {
        int leader = __ffsll((long long)mask) - 1;
        int base = 0;
        if (lane == leader) base = atomicAdd(cnt, __popcll(mask));
        base = __shfl(base, leader, 64);
        if (in) {
            int off = __popcll(mask & ((1ull << lane) - 1ull));
            int q = base + off;
            if (q < CAP) list[q] = a;
        }
    }
}

// K1: block = (chunk c, gt-group gg), 8 waves. Also zeroes d_out (grid-stride).
// Phase A: in-box test only; wave-aggregated append to per-GT LDS lists.
// Phase B: wave j evaluates GT j's candidates into per-lane sorted top-10,
// then 10 rounds of register-only wave-butterfly selection.
__global__ __launch_bounds__(BLK) void topk_partial_kernel(
    const float* __restrict__ pd_scores,
    const float* __restrict__ pd_bboxes,
    const float* __restrict__ anc_points,
    const float* __restrict__ gt_bboxes,
    float* __restrict__ pval,
    int*   __restrict__ pidx,
    int*   __restrict__ out_zero)      // d_out base: 2*NUM_A ints to zero
{
    const int c   = blockIdx.x;
    const int gg  = blockIdx.y;
    const int tid = threadIdx.x;
    const int g0  = gg * GGROUP;

    // ---- zero d_out (replaces the hipMemsetAsync node) ----
    {
        const int bid = blockIdx.y * gridDim.x + blockIdx.x;   // 0..511
        const int t   = bid * BLK + tid;                       // 0..262143
        int4* o4 = (int4*)out_zero;
        if (t < (2 * NUM_A) / 4) o4[t] = make_int4(0, 0, 0, 0); // 200000 int4
    }

    __shared__ int s_cnt[GGROUP];
    __shared__ int s_cand[GGROUP][CAP];

    if (tid < GGROUP) s_cnt[tid] = 0;

    float gx1[GGROUP], gy1[GGROUP], gx2[GGROUP], gy2[GGROUP];
#pragma unroll
    for (int j = 0; j < GGROUP; ++j) {
        float4 gb = ((const float4*)gt_bboxes)[g0 + j];
        gx1[j] = gb.x; gy1[j] = gb.y; gx2[j] = gb.z; gy2[j] = gb.w;
    }
    __syncthreads();

    const int lane = tid & 63;

    // ---- Phase A: candidate collection (uniform trip count: ballots in
    // uniform control flow; validity folded into the predicates) ----
    const int p0 = c * (CHUNK_SZ / 2);          // float4 = 2 anchors
    const int p1 = p0 + CHUNK_SZ / 2;           // 3125 quads per chunk
    const int niter = (CHUNK_SZ / 2 + BLK - 1) / BLK;   // 7
    for (int it = 0; it < niter; ++it) {
        const int p = p0 + it * BLK + tid;
        const bool valid = (p < p1);
        const int pc = valid ? p : (p1 - 1);    // clamp: in-bounds load
        float4 aq = ((const float4*)anc_points)[pc];
        const int a2 = 2 * pc;
#pragma unroll
        for (int j = 0; j < GGROUP; ++j) {
            bool in0 = valid &&
                       (aq.x >= gx1[j]) && (aq.x <= gx2[j]) &&
                       (aq.y >= gy1[j]) && (aq.y <= gy2[j]);
            bool in1 = valid &&
                       (aq.z >= gx1[j]) && (aq.z <= gx2[j]) &&
                       (aq.w >= gy1[j]) && (aq.w <= gy2[j]);
            ballot_append(in0, a2,     &s_cnt[j], s_cand[j], lane);
            ballot_append(in1, a2 + 1, &s_cnt[j], s_cand[j], lane);
        }
    }
    __syncthreads();

    // ---- Phase B: wave j evaluates GT j's candidates ----
    const int wj = tid >> 6;                    // wave = GT within group

    float4 gb = ((const float4*)gt_bboxes)[g0 + wj];   // wave-uniform
    const float garea = (gb.z - gb.x) * (gb.w - gb.y);
    const int n = min(s_cnt[wj], CAP);

    float tv[TOPK]; int ti[TOPK];
#pragma unroll
    for (int k = 0; k < TOPK; ++k) { tv[k] = 0.0f; ti[k] = SENT_I; }

    for (int i = lane; i < n; i += 64) {
        const int a = s_cand[wj][i];
        float4 pb = ((const float4*)pd_bboxes)[a];
        float sc = pd_scores[a];
        float parea = (pb.z - pb.x) * (pb.w - pb.y);
        float m = iou_metric(pb.x, pb.y, pb.z, pb.w, parea, sc,
                             gb.x, gb.y, gb.z, gb.w, garea);
        // candidate order is append order -> need full (v,idx) compare
        if (better(m, a, tv[TOPK - 1], ti[TOPK - 1])) {
#pragma unroll
            for (int k = TOPK - 1; k >= 1; --k) {
                bool gp = better(m, a, tv[k - 1], ti[k - 1]);
                bool gc = better(m, a, tv[k],     ti[k]);
                tv[k] = gp ? tv[k - 1] : (gc ? m : tv[k]);
                ti[k] = gp ? ti[k - 1] : (gc ? a : ti[k]);
            }
            if (better(m, a, tv[0], ti[0])) { tv[0] = m; ti[0] = a; }
        }
    }

    // ---- 10-round wave selection: 64 sorted lists -> global top-10 ----
    float outv = 0.0f; int outi = SENT_I;
#pragma unroll
    for (int k = 0; k < TOPK; ++k) {
        float bv = tv[0]; int bi = ti[0];
        wave_max_pair(bv, bi);
        bool win = (ti[0] == bi);   // unique real anchor id; sentinel benign
#pragma unroll
        for (int j = 0; j < TOPK - 1; ++j) {
            tv[j] = win ? tv[j + 1] : tv[j];
            ti[j] = win ? ti[j + 1] : ti[j];
        }
        if (win) { tv[TOPK - 1] = 0.0f; ti[TOPK - 1] = SENT_I; }
        if (lane == k) { outv = bv; outi = bi; }
    }
    if (lane < TOPK) {
        const int g = g0 + wj;
        pval[(g * CHUNKS + c) * TOPK + lane] = outv;
        pidx[(g * CHUNKS + c) * TOPK + lane] = outi;
    }
}

// K2: one block (one wave) per GT. Lane t holds chunk t's sorted 10-list;
// 10 rounds of wave selection -> exact top-10. For each positive winner
// (wave-uniform), all 64 lanes compute that anchor's metric against THEIR
// OWN GT and butterfly-argmax (m, g) -> out_idx; out_fg set. Duplicate
// winners across GT columns write identical values — benign race.
__global__ __launch_bounds__(64) void merge_assign_kernel(
    const float* __restrict__ pval,
    const int*   __restrict__ pidx,
    const float* __restrict__ pd_scores,
    const float* __restrict__ pd_bboxes,
    const float* __restrict__ anc_points,
    const float* __restrict__ gt_bboxes,
    int* __restrict__ out_fg,
    int* __restrict__ out_idx)
{
    const int g    = blockIdx.x;
    const int lane = threadIdx.x;   // == chunk for loading; == GT for argmax

    float4 mygt = ((const float4*)gt_bboxes)[lane];
    float  myga = (mygt.z - mygt.x) * (mygt.w - mygt.y);

    float tv[TOPK]; int ti[TOPK];
    const float* pv = pval + (g * CHUNKS + lane) * TOPK;
    const int*   pi = pidx + (g * CHUNKS + lane) * TOPK;
#pragma unroll
    for (int k = 0; k < TOPK; ++k) { tv[k] = pv[k]; ti[k] = pi[k]; }

#pragma unroll
    for (int k = 0; k < TOPK; ++k) {
        float bv = tv[0]; int bi = ti[0];
        wave_max_pair(bv, bi);
        bool win = (ti[0] == bi);
#pragma unroll
        for (int j = 0; j < TOPK - 1; ++j) {
            tv[j] = win ? tv[j + 1] : tv[j];
            ti[j] = win ? ti[j + 1] : ti[j];
        }
        if (win) { tv[TOPK - 1] = 0.0f; ti[TOPK - 1] = SENT_I; }

        if (bv > 0.0f) {            // wave-uniform: winner k is foreground
            const int a = bi;
            float2 ap = ((const float2*)anc_points)[a];   // uniform -> s_load
            float4 pb = ((const float4*)pd_bboxes)[a];
            float  sc = pd_scores[a];
            float parea = (pb.z - pb.x) * (pb.w - pb.y);
            bool in = (ap.x >= mygt.x) && (ap.x <= mygt.z) &&
                      (ap.y >= mygt.y) && (ap.y <= mygt.w);
            float m = iou_metric(pb.x, pb.y, pb.z, pb.w, parea,
                                 in ? sc : 0.0f,   // exact-0 when outside
                                 mygt.x, mygt.y, mygt.z, mygt.w, myga);
            // butterfly argmax over (m, gt=lane); lowest g on ties = first-max
            float av = m; int ag = lane;
#pragma unroll
            for (int s = 1; s < 64; s <<= 1) {
                float ov = __shfl_xor(av, s, 64);
                int   og = __shfl_xor(ag, s, 64);
                if ((ov > av) || ((ov == av) && (og < ag))) { av = ov; ag = og; }
            }
            if (lane == 0) { out_fg[a] = 1; out_idx[a] = ag; }
        }
    }
}

extern "C" void kernel_launch(void* const* d_in, const int* in_sizes, int n_in,
                              void* d_out, int out_size, void* d_ws, size_t ws_size,
                              hipStream_t stream) {
    const float* pd_scores  = (const float*)d_in[0];   // (A,1) f32
    const float* pd_bboxes  = (const float*)d_in[1];   // (A,4) f32
    const float* anc_points = (const float*)d_in[2];   // (A,2) f32
    // d_in[3] = gt_labels (G,) int32 — unused (NUM_CLASSES==1 -> all 0)
    const float* gt_bboxes  = (const float*)d_in[4];   // (G,4) f32

    const int npairs = NUM_G * CHUNKS * TOPK;          // 40960
    float* pval = (float*)d_ws;                        // 160 KB
    int*   pidx = (int*)(pval + npairs);               // 160 KB

    int* out_fg  = (int*)d_out;            // [fg(A) | idx(A)] as int32
    int* out_idx = out_fg + NUM_A;

    dim3 g1(CHUNKS, NGROUPS);              // 64 x 8 = 512 blocks
    topk_partial_kernel<<<g1, BLK, 0, stream>>>(
        pd_scores, pd_bboxes, anc_points, gt_bboxes, pval, pidx,
        (int*)d_out);
    merge_assign_kernel<<<NUM_G, 64, 0, stream>>>(
        pval, pidx, pd_scores, pd_bboxes, anc_points, gt_bboxes,
        out_fg, out_idx);
}

// Round 9
// 108.875 us; speedup vs baseline: 1.0224x; 1.0224x over previous
//
#include <hip/hip_runtime.h>

#define NUM_A    400000
#define NUM_G    64
#define TOPK     10
#define CHUNKS   64
#define CHUNK_SZ (NUM_A / CHUNKS)   // 6250
#define GGROUP   4                  // GTs per K1 block (= waves per block)
#define NGROUPS  (NUM_G / GGROUP)   // 16
#define CAP      768                // per-GT candidate cap per chunk
                                    // (mean in-box <= 250, SD ~16 -> 32 SD margin)
#define SENT_I   0x7fffffff

// top_k ordering: larger value first; ties -> lower anchor index first.
// Sentinel (0.0f, SENT_I) sorts after every real candidate.
__device__ __forceinline__ bool better(float m1, int a1, float m2, int a2) {
    return (m1 > m2) || ((m1 == m2) && (a1 < a2));
}

// IoU-metric; arithmetic order identical to rounds 2-8 (absmax=0 vs numpy).
__device__ __forceinline__ float iou_metric(
    float px1, float py1, float px2, float py2, float parea, float score,
    float gx1, float gy1, float gx2, float gy2, float garea)
{
    float ltx = fmaxf(px1, gx1);
    float lty = fmaxf(py1, gy1);
    float rbx = fminf(px2, gx2);
    float rby = fminf(py2, gy2);
    float w = fmaxf(rbx - ltx, 0.0f);
    float h = fmaxf(rby - lty, 0.0f);
    float inter = w * h;
    float iou = inter / (parea + garea - inter);   // denom >= 64 always
    float iou2 = iou * iou;
    float iou6 = iou2 * iou2 * iou2;
    return score * iou6;
}

// Wave-wide (64-lane) butterfly max of (value, anchor) under better().
__device__ __forceinline__ void wave_max_pair(float& bv, int& bi) {
#pragma unroll
    for (int s = 1; s < 64; s <<= 1) {
        float ov = __shfl_xor(bv, s, 64);
        int   oi = __shfl_xor(bi, s, 64);
        if (better(ov, oi, bv, bi)) { bv = ov; bi = oi; }
    }
}

// K1: block = (chunk c, gt-group gg), 4 waves (round-7 structure — the R8
// ballot/GGROUP=8 variant regressed: uniform ballots cost more VALU than the
// execz-skipped divergent appends, and 8-wave blocks halved occupancy).
// Also zeroes d_out (grid-stride), replacing the hipMemsetAsync node.
__global__ __launch_bounds__(256) void topk_partial_kernel(
    const float* __restrict__ pd_scores,
    const float* __restrict__ pd_bboxes,
    const float* __restrict__ anc_points,
    const float* __restrict__ gt_bboxes,
    float* __restrict__ pval,
    int*   __restrict__ pidx,
    int*   __restrict__ out_zero)      // d_out base: 2*NUM_A ints to zero
{
    const int c   = blockIdx.x;
    const int gg  = blockIdx.y;
    const int tid = threadIdx.x;
    const int g0  = gg * GGROUP;

    // ---- zero d_out: 1024 blocks x 256 thr >= 200000 int4 ----
    {
        const int bid = blockIdx.y * gridDim.x + blockIdx.x;   // 0..1023
        const int t   = bid * 256 + tid;                       // 0..262143
        if (t < (2 * NUM_A) / 4) ((int4*)out_zero)[t] = make_int4(0, 0, 0, 0);
    }

    __shared__ int s_cnt[GGROUP];
    __shared__ int s_cand[GGROUP][CAP];

    if (tid < GGROUP) s_cnt[tid] = 0;

    float gx1[GGROUP], gy1[GGROUP], gx2[GGROUP], gy2[GGROUP];
#pragma unroll
    for (int j = 0; j < GGROUP; ++j) {
        float4 gb = ((const float4*)gt_bboxes)[g0 + j];
        gx1[j] = gb.x; gy1[j] = gb.y; gx2[j] = gb.z; gy2[j] = gb.w;
    }
    __syncthreads();

    // ---- Phase A: candidate collection (divergent appends, but ONE atomic
    // per GT per anchor-quad: half the branch sites / LDS atomics of R7) ----
    const int p0 = c * (CHUNK_SZ / 2);          // float4 = 2 anchors
    const int p1 = p0 + CHUNK_SZ / 2;
    for (int p = p0 + tid; p < p1; p += 256) {
        float4 aq = ((const float4*)anc_points)[p];
        const int a2 = 2 * p;
#pragma unroll
        for (int j = 0; j < GGROUP; ++j) {
            bool in0 = (aq.x >= gx1[j]) && (aq.x <= gx2[j]) &&
                       (aq.y >= gy1[j]) && (aq.y <= gy2[j]);
            bool in1 = (aq.z >= gx1[j]) && (aq.z <= gx2[j]) &&
                       (aq.w >= gy1[j]) && (aq.w <= gy2[j]);
            const int nh = (in0 ? 1 : 0) + (in1 ? 1 : 0);
            if (nh) {
                int q = atomicAdd(&s_cnt[j], nh);
                if (in0 && q < CAP) { s_cand[j][q] = a2; q++; }
                if (in1 && q < CAP) { s_cand[j][q] = a2 + 1; }
            }
        }
    }
    __syncthreads();

    // ---- Phase B: wave j evaluates GT j's candidates ----
    const int wj   = tid >> 6;     // wave = GT within group
    const int lane = tid & 63;

    float4 gb = ((const float4*)gt_bboxes)[g0 + wj];   // wave-uniform
    const float garea = (gb.z - gb.x) * (gb.w - gb.y);
    const int n = min(s_cnt[wj], CAP);

    float tv[TOPK]; int ti[TOPK];
#pragma unroll
    for (int k = 0; k < TOPK; ++k) { tv[k] = 0.0f; ti[k] = SENT_I; }

    for (int i = lane; i < n; i += 64) {
        const int a = s_cand[wj][i];
        float4 pb = ((const float4*)pd_bboxes)[a];
        float sc = pd_scores[a];
        float parea = (pb.z - pb.x) * (pb.w - pb.y);
        float m = iou_metric(pb.x, pb.y, pb.z, pb.w, parea, sc,
                             gb.x, gb.y, gb.z, gb.w, garea);
        // candidate order is append order -> need full (v,idx) compare
        if (better(m, a, tv[TOPK - 1], ti[TOPK - 1])) {
#pragma unroll
            for (int k = TOPK - 1; k >= 1; --k) {
                bool gp = better(m, a, tv[k - 1], ti[k - 1]);
                bool gc = better(m, a, tv[k],     ti[k]);
                tv[k] = gp ? tv[k - 1] : (gc ? m : tv[k]);
                ti[k] = gp ? ti[k - 1] : (gc ? a : ti[k]);
            }
            if (better(m, a, tv[0], ti[0])) { tv[0] = m; ti[0] = a; }
        }
    }

    // ---- 10-round wave selection: 64 sorted lists -> global top-10 ----
    float outv = 0.0f; int outi = SENT_I;
#pragma unroll
    for (int k = 0; k < TOPK; ++k) {
        float bv = tv[0]; int bi = ti[0];
        wave_max_pair(bv, bi);
        bool win = (ti[0] == bi);   // unique real anchor id; sentinel benign
#pragma unroll
        for (int j = 0; j < TOPK - 1; ++j) {
            tv[j] = win ? tv[j + 1] : tv[j];
            ti[j] = win ? ti[j + 1] : ti[j];
        }
        if (win) { tv[TOPK - 1] = 0.0f; ti[TOPK - 1] = SENT_I; }
        if (lane == k) { outv = bv; outi = bi; }
    }
    if (lane < TOPK) {
        const int g = g0 + wj;
        pval[(g * CHUNKS + c) * TOPK + lane] = outv;
        pidx[(g * CHUNKS + c) * TOPK + lane] = outi;
    }
}

// K2: one block (one wave) per GT. Lane t holds chunk t's sorted 10-list;
// 10 rounds of wave selection -> exact top-10. For each positive winner
// (wave-uniform), all 64 lanes compute that anchor's metric against THEIR
// OWN GT and butterfly-argmax (m, g) -> out_idx; out_fg set. Duplicate
// winners across GT columns write identical values — benign race.
__global__ __launch_bounds__(64) void merge_assign_kernel(
    const float* __restrict__ pval,
    const int*   __restrict__ pidx,
    const float* __restrict__ pd_scores,
    const float* __restrict__ pd_bboxes,
    const float* __restrict__ anc_points,
    const float* __restrict__ gt_bboxes,
    int* __restrict__ out_fg,
    int* __restrict__ out_idx)
{
    const int g    = blockIdx.x;
    const int lane = threadIdx.x;   // == chunk for loading; == GT for argmax

    float4 mygt = ((const float4*)gt_bboxes)[lane];
    float  myga = (mygt.z - mygt.x) * (mygt.w - mygt.y);

    float tv[TOPK]; int ti[TOPK];
    const float* pv = pval + (g * CHUNKS + lane) * TOPK;
    const int*   pi = pidx + (g * CHUNKS + lane) * TOPK;
#pragma unroll
    for (int k = 0; k < TOPK; ++k) { tv[k] = pv[k]; ti[k] = pi[k]; }

#pragma unroll
    for (int k = 0; k < TOPK; ++k) {
        float bv = tv[0]; int bi = ti[0];
        wave_max_pair(bv, bi);
        bool win = (ti[0] == bi);
#pragma unroll
        for (int j = 0; j < TOPK - 1; ++j) {
            tv[j] = win ? tv[j + 1] : tv[j];
            ti[j] = win ? ti[j + 1] : ti[j];
        }
        if (win) { tv[TOPK - 1] = 0.0f; ti[TOPK - 1] = SENT_I; }

        if (bv > 0.0f) {            // wave-uniform: winner k is foreground
            const int a = bi;
            float2 ap = ((const float2*)anc_points)[a];   // uniform -> s_load
            float4 pb = ((const float4*)pd_bboxes)[a];
            float  sc = pd_scores[a];
            float parea = (pb.z - pb.x) * (pb.w - pb.y);
            bool in = (ap.x >= mygt.x) && (ap.x <= mygt.z) &&
                      (ap.y >= mygt.y) && (ap.y <= mygt.w);
            float m = iou_metric(pb.x, pb.y, pb.z, pb.w, parea,
                                 in ? sc : 0.0f,   // exact-0 when outside
                                 mygt.x, mygt.y, mygt.z, mygt.w, myga);
            // butterfly argmax over (m, gt=lane); lowest g on ties = first-max
            float av = m; int ag = lane;
#pragma unroll
            for (int s = 1; s < 64; s <<= 1) {
                float ov = __shfl_xor(av, s, 64);
                int   og = __shfl_xor(ag, s, 64);
                if ((ov > av) || ((ov == av) && (og < ag))) { av = ov; ag = og; }
            }
            if (lane == 0) { out_fg[a] = 1; out_idx[a] = ag; }
        }
    }
}

extern "C" void kernel_launch(void* const* d_in, const int* in_sizes, int n_in,
                              void* d_out, int out_size, void* d_ws, size_t ws_size,
                              hipStream_t stream) {
    const float* pd_scores  = (const float*)d_in[0];   // (A,1) f32
    const float* pd_bboxes  = (const float*)d_in[1];   // (A,4) f32
    const float* anc_points = (const float*)d_in[2];   // (A,2) f32
    // d_in[3] = gt_labels (G,) int32 — unused (NUM_CLASSES==1 -> all 0)
    const float* gt_bboxes  = (const float*)d_in[4];   // (G,4) f32

    const int npairs = NUM_G * CHUNKS * TOPK;          // 40960
    float* pval = (float*)d_ws;                        // 160 KB
    int*   pidx = (int*)(pval + npairs);               // 160 KB

    int* out_fg  = (int*)d_out;            // [fg(A) | idx(A)] as int32
    int* out_idx = out_fg + NUM_A;

    dim3 g1(CHUNKS, NGROUPS);              // 64 x 16 = 1024 blocks
    topk_partial_kernel<<<g1, 256, 0, stream>>>(
        pd_scores, pd_bboxes, anc_points, gt_bboxes, pval, pidx,
        (int*)d_out);
    merge_assign_kernel<<<NUM_G, 64, 0, stream>>>(
        pval, pidx, pd_scores, pd_bboxes, anc_points, gt_bboxes,
        out_fg, out_idx);
}

// Round 10
// 105.146 us; speedup vs baseline: 1.0587x; 1.0355x over previous
//
#include <hip/hip_runtime.h>

#define NUM_A    400000
#define NUM_G    64
#define TOPK     10
#define CHUNKS   64
#define CHUNK_SZ (NUM_A / CHUNKS)   // 6250
#define GGROUP   4                  // GTs per K1 block (= waves per block)
#define NGROUPS  (NUM_G / GGROUP)   // 16
#define CAP      768                // per-GT candidate cap per chunk
                                    // (mean in-box <= 250, SD ~15 -> 33 SD margin)
#define SENT_I   0x7fffffff

// top_k ordering: larger value first; ties -> lower anchor index first.
// Sentinel (0.0f, SENT_I) sorts after every real candidate (real zero-metric
// candidates have a < SENT_I).
__device__ __forceinline__ bool better(float m1, int a1, float m2, int a2) {
    return (m1 > m2) || ((m1 == m2) && (a1 < a2));
}

// IoU-metric; arithmetic order identical to rounds 2-9 (absmax=0 vs numpy).
__device__ __forceinline__ float iou_metric(
    float px1, float py1, float px2, float py2, float parea, float score,
    float gx1, float gy1, float gx2, float gy2, float garea)
{
    float ltx = fmaxf(px1, gx1);
    float lty = fmaxf(py1, gy1);
    float rbx = fminf(px2, gx2);
    float rby = fminf(py2, gy2);
    float w = fmaxf(rbx - ltx, 0.0f);
    float h = fmaxf(rby - lty, 0.0f);
    float inter = w * h;
    float iou = inter / (parea + garea - inter);   // denom >= 64 always
    float iou2 = iou * iou;
    float iou6 = iou2 * iou2 * iou2;
    return score * iou6;
}

// Wave-wide (64-lane) butterfly max of (value, anchor) under better().
__device__ __forceinline__ void wave_max_pair(float& bv, int& bi) {
#pragma unroll
    for (int s = 1; s < 64; s <<= 1) {
        float ov = __shfl_xor(bv, s, 64);
        int   oi = __shfl_xor(bi, s, 64);
        if (better(ov, oi, bv, bi)) { bv = ov; bi = oi; }
    }
}

// K1: block = (chunk c, gt-group gg), 4 waves.  [R7 structure — best measured:
// R8's ballot append (uniform VALU > divergent execz-skipped segments) and
// R9's fused d_out zero + combined atomic both regressed.]
// Phase A: in-box test only; append hits to per-GT LDS candidate lists.
// Phase B: wave j evaluates GT j's candidates into per-lane sorted top-10,
// then 10 rounds of register-only wave-butterfly selection.
__global__ __launch_bounds__(256) void topk_partial_kernel(
    const float* __restrict__ pd_scores,
    const float* __restrict__ pd_bboxes,
    const float* __restrict__ anc_points,
    const float* __restrict__ gt_bboxes,
    float* __restrict__ pval,
    int*   __restrict__ pidx)
{
    const int c   = blockIdx.x;
    const int gg  = blockIdx.y;
    const int tid = threadIdx.x;
    const int g0  = gg * GGROUP;

    __shared__ int s_cnt[GGROUP];
    __shared__ int s_cand[GGROUP][CAP];

    if (tid < GGROUP) s_cnt[tid] = 0;

    float gx1[GGROUP], gy1[GGROUP], gx2[GGROUP], gy2[GGROUP];
#pragma unroll
    for (int j = 0; j < GGROUP; ++j) {
        float4 gb = ((const float4*)gt_bboxes)[g0 + j];
        gx1[j] = gb.x; gy1[j] = gb.y; gx2[j] = gb.z; gy2[j] = gb.w;
    }
    __syncthreads();

    // ---- Phase A: candidate collection ----
    const int p0 = c * (CHUNK_SZ / 2);          // float4 = 2 anchors
    const int p1 = p0 + CHUNK_SZ / 2;
    for (int p = p0 + tid; p < p1; p += 256) {
        float4 aq = ((const float4*)anc_points)[p];
        const int a2 = 2 * p;
#pragma unroll
        for (int j = 0; j < GGROUP; ++j) {
            bool in0 = (aq.x >= gx1[j]) && (aq.x <= gx2[j]) &&
                       (aq.y >= gy1[j]) && (aq.y <= gy2[j]);
            bool in1 = (aq.z >= gx1[j]) && (aq.z <= gx2[j]) &&
                       (aq.w >= gy1[j]) && (aq.w <= gy2[j]);
            if (in0) { int q = atomicAdd(&s_cnt[j], 1); if (q < CAP) s_cand[j][q] = a2; }
            if (in1) { int q = atomicAdd(&s_cnt[j], 1); if (q < CAP) s_cand[j][q] = a2 + 1; }
        }
    }
    __syncthreads();

    // ---- Phase B: per-wave candidate evaluation ----
    const int wj   = tid >> 6;     // wave = GT within group
    const int lane = tid & 63;

    float4 gb = ((const float4*)gt_bboxes)[g0 + wj];   // wave-uniform
    const float garea = (gb.z - gb.x) * (gb.w - gb.y);
    const int n = min(s_cnt[wj], CAP);

    float tv[TOPK]; int ti[TOPK];
#pragma unroll
    for (int k = 0; k < TOPK; ++k) { tv[k] = 0.0f; ti[k] = SENT_I; }

    for (int i = lane; i < n; i += 64) {
        const int a = s_cand[wj][i];
        float4 pb = ((const float4*)pd_bboxes)[a];
        float sc = pd_scores[a];
        float parea = (pb.z - pb.x) * (pb.w - pb.y);
        float m = iou_metric(pb.x, pb.y, pb.z, pb.w, parea, sc,
                             gb.x, gb.y, gb.z, gb.w, garea);
        // candidate order is atomic-append order -> need full (v,idx) compare
        if (better(m, a, tv[TOPK - 1], ti[TOPK - 1])) {
#pragma unroll
            for (int k = TOPK - 1; k >= 1; --k) {
                bool gp = better(m, a, tv[k - 1], ti[k - 1]);
                bool gc = better(m, a, tv[k],     ti[k]);
                tv[k] = gp ? tv[k - 1] : (gc ? m : tv[k]);
                ti[k] = gp ? ti[k - 1] : (gc ? a : ti[k]);
            }
            if (better(m, a, tv[0], ti[0])) { tv[0] = m; ti[0] = a; }
        }
    }

    // ---- 10-round wave selection: 64 sorted lists -> global top-10 ----
    float outv = 0.0f; int outi = SENT_I;
#pragma unroll
    for (int k = 0; k < TOPK; ++k) {
        float bv = tv[0]; int bi = ti[0];
        wave_max_pair(bv, bi);
        // owner lane (unique real anchor id; sentinel-shift is harmless) pops
        bool win = (ti[0] == bi);
#pragma unroll
        for (int j = 0; j < TOPK - 1; ++j) {
            tv[j] = win ? tv[j + 1] : tv[j];
            ti[j] = win ? ti[j + 1] : ti[j];
        }
        if (win) { tv[TOPK - 1] = 0.0f; ti[TOPK - 1] = SENT_I; }
        if (lane == k) { outv = bv; outi = bi; }
    }
    if (lane < TOPK) {
        const int g = g0 + wj;
        pval[(g * CHUNKS + c) * TOPK + lane] = outv;
        pidx[(g * CHUNKS + c) * TOPK + lane] = outi;
    }
}

// K2: one block (one wave) per GT. Lane t holds chunk t's sorted 10-list;
// 10 rounds of wave selection give the exact top-10. For each positive
// winner (wave-uniform), all 64 lanes compute that anchor's metric against
// THEIR OWN GT and butterfly-argmax (m, g) -> out_idx; out_fg set.
// Duplicate winners across GT columns write identical values — benign.
__global__ __launch_bounds__(64) void merge_assign_kernel(
    const float* __restrict__ pval,
    const int*   __restrict__ pidx,
    const float* __restrict__ pd_scores,
    const float* __restrict__ pd_bboxes,
    const float* __restrict__ anc_points,
    const float* __restrict__ gt_bboxes,
    int* __restrict__ out_fg,
    int* __restrict__ out_idx)
{
    const int g    = blockIdx.x;
    const int lane = threadIdx.x;   // == chunk for loading; == GT for argmax

    float4 mygt = ((const float4*)gt_bboxes)[lane];
    float  myga = (mygt.z - mygt.x) * (mygt.w - mygt.y);

    float tv[TOPK]; int ti[TOPK];
    const float* pv = pval + (g * CHUNKS + lane) * TOPK;
    const int*   pi = pidx + (g * CHUNKS + lane) * TOPK;
#pragma unroll
    for (int k = 0; k < TOPK; ++k) { tv[k] = pv[k]; ti[k] = pi[k]; }

#pragma unroll
    for (int k = 0; k < TOPK; ++k) {
        float bv = tv[0]; int bi = ti[0];
        wave_max_pair(bv, bi);
        bool win = (ti[0] == bi);
#pragma unroll
        for (int j = 0; j < TOPK - 1; ++j) {
            tv[j] = win ? tv[j + 1] : tv[j];
            ti[j] = win ? ti[j + 1] : ti[j];
        }
        if (win) { tv[TOPK - 1] = 0.0f; ti[TOPK - 1] = SENT_I; }

        if (bv > 0.0f) {            // wave-uniform: winner k is foreground
            const int a = bi;
            float2 ap = ((const float2*)anc_points)[a];   // uniform -> s_load
            float4 pb = ((const float4*)pd_bboxes)[a];
            float  sc = pd_scores[a];
            float parea = (pb.z - pb.x) * (pb.w - pb.y);
            bool in = (ap.x >= mygt.x) && (ap.x <= mygt.z) &&
                      (ap.y >= mygt.y) && (ap.y <= mygt.w);
            float m = iou_metric(pb.x, pb.y, pb.z, pb.w, parea,
                                 in ? sc : 0.0f,   // exact-0 when outside
                                 mygt.x, mygt.y, mygt.z, mygt.w, myga);
            // butterfly argmax over (m, gt=lane); lowest g on ties = first-max
            float av = m; int ag = lane;
#pragma unroll
            for (int s = 1; s < 64; s <<= 1) {
                float ov = __shfl_xor(av, s, 64);
                int   og = __shfl_xor(ag, s, 64);
                if ((ov > av) || ((ov == av) && (og < ag))) { av = ov; ag = og; }
            }
            if (lane == 0) { out_fg[a] = 1; out_idx[a] = ag; }
        }
    }
}

extern "C" void kernel_launch(void* const* d_in, const int* in_sizes, int n_in,
                              void* d_out, int out_size, void* d_ws, size_t ws_size,
                              hipStream_t stream) {
    const float* pd_scores  = (const float*)d_in[0];   // (A,1) f32
    const float* pd_bboxes  = (const float*)d_in[1];   // (A,4) f32
    const float* anc_points = (const float*)d_in[2];   // (A,2) f32
    // d_in[3] = gt_labels (G,) int32 — unused (NUM_CLASSES==1 -> all 0)
    const float* gt_bboxes  = (const float*)d_in[4];   // (G,4) f32

    const int npairs = NUM_G * CHUNKS * TOPK;          // 40960
    float* pval = (float*)d_ws;                        // 160 KB
    int*   pidx = (int*)(pval + npairs);               // 160 KB

    int* out_fg  = (int*)d_out;            // [fg(A) | idx(A)] as int32
    int* out_idx = out_fg + NUM_A;

    // zero BOTH output halves: non-winners get fg=0, idx=0
    hipMemsetAsync(d_out, 0, 2 * NUM_A * sizeof(int), stream);

    dim3 g1(CHUNKS, NGROUPS);              // 64 x 16 = 1024 blocks
    topk_partial_kernel<<<g1, 256, 0, stream>>>(
        pd_scores, pd_bboxes, anc_points, gt_bboxes, pval, pidx);
    merge_assign_kernel<<<NUM_G, 64, 0, stream>>>(
        pval, pidx, pd_scores, pd_bboxes, anc_points, gt_bboxes,
        out_fg, out_idx);
}